// Round 11
// baseline (113.595 us; speedup 1.0000x reference)
//
#include <hip/hip_runtime.h>

#define Bv 4
#define Vv 50000
#define Cv 160
#define TILES 782       // ceil(Vv/64)
#define VPAD  50048     // TILES*64, keeps WT rows 256B-aligned

// Kernel 1: per-(b,c) affine table A[b][c][12]:
//   A[0..8]  = R row-major (rows b1,b2,b3)
//   A[9..11] = center + V_nodes - R*center
// so out[b,v,:] = M·x_v + t with [M|t] = sum_c W[v,c]*A[b,c,:]
__global__ void precompute_A(const float* __restrict__ X,
                             const float* __restrict__ Vn,
                             const float* __restrict__ r6,
                             const int* __restrict__ idx,
                             float* __restrict__ A) {
    int i = blockIdx.x * blockDim.x + threadIdx.x;
    if (i >= Bv * Cv) return;
    int b = i / Cv, c = i % Cv;

    const float* d6 = r6 + (size_t)(b * Cv + c) * 6;
    float a1x = d6[0], a1y = d6[1], a1z = d6[2];
    float a2x = d6[3], a2y = d6[4], a2z = d6[5];

    float n1 = fmaxf(sqrtf(a1x*a1x + a1y*a1y + a1z*a1z), 1e-8f);
    float b1x = a1x / n1, b1y = a1y / n1, b1z = a1z / n1;

    float d = b1x*a2x + b1y*a2y + b1z*a2z;
    float px = a2x - d*b1x, py = a2y - d*b1y, pz = a2z - d*b1z;
    float n2 = fmaxf(sqrtf(px*px + py*py + pz*pz), 1e-8f);
    float b2x = px / n2, b2y = py / n2, b2z = pz / n2;

    float b3x = b1y*b2z - b1z*b2y;
    float b3y = b1z*b2x - b1x*b2z;
    float b3z = b1x*b2y - b1y*b2x;

    int iv = idx[c];
    const float* xc = X + ((size_t)b * Vv + iv) * 3;
    float cx = xc[0], cy = xc[1], cz = xc[2];
    const float* vn = Vn + (size_t)(b * Cv + c) * 3;
    float vx = vn[0], vy = vn[1], vz = vn[2];

    float* Ao = A + (size_t)(b * Cv + c) * 12;
    Ao[0] = b1x; Ao[1] = b1y; Ao[2] = b1z;
    Ao[3] = b2x; Ao[4] = b2y; Ao[5] = b2z;
    Ao[6] = b3x; Ao[7] = b3y; Ao[8] = b3z;
    Ao[9]  = cx + vx - (b1x*cx + b1y*cy + b1z*cz);
    Ao[10] = cy + vy - (b2x*cx + b2y*cy + b2z*cz);
    Ao[11] = cz + vz - (b3x*cx + b3y*cy + b3z*cz);
}

// Kernel 1b: W (V x C row-major) -> WT (C x VPAD). After this, a wave
// reading WT[c][v0..v0+63] is ONE coalesced global_load_dword = 2 cache
// lines, vs 64 lines/instr for the row-major per-lane gather (the ~13 us
// structural cost common to R4-R10).
__global__ __launch_bounds__(256) void transpose_W(const float* __restrict__ W,
                                                   float* __restrict__ WT) {
    __shared__ float T[64 * 165];   // [v][c], stride 165 breaks write/read bank alias
    const int tid = threadIdx.x;
    const int v0  = blockIdx.x * 64;

    // Read 64 rows x 40 float4, coalesced along rows.
    for (int i = tid; i < 64 * 40; i += 256) {
        int r = i / 40, c4 = i % 40;
        int row = v0 + r;
        if (row >= Vv) row = Vv - 1;   // pad rows replicate last row (harmless)
        float4 q = ((const float4*)(W + (size_t)row * Cv))[c4];
        float* t = &T[r * 165 + c4 * 4];
        t[0] = q.x; t[1] = q.y; t[2] = q.z; t[3] = q.w;
    }
    __syncthreads();

    // Write 160 c-rows x 64 v, coalesced over v (16 threads x float4 per c).
    for (int i = tid; i < Cv * 16; i += 256) {
        int c = i / 16, g = i % 16;
        float4 q;
        q.x = T[(g * 4 + 0) * 165 + c];
        q.y = T[(g * 4 + 1) * 165 + c];
        q.z = T[(g * 4 + 2) * 165 + c];
        q.w = T[(g * 4 + 3) * 165 + c];
        ((float4*)(WT + (size_t)c * VPAD + v0))[g] = q;
    }
}

// Kernel 2: R7 structure (the measured best, ~29 us) with the WT read.
// 782 blocks x 512 thr = 8 waves: wave w -> (batch b = w&3, K-half h = w>>2,
// c in [80h, 80h+80)); lane = vertex. One block covers ALL batches+halves of
// a tile -> W enters exactly one XCD L2 (no R9-style duplication).
// W: coalesced dword from WT (vmcnt). A: blockwise-uniform -> s_load
// (scalar pipe, lgkmcnt — independent counter). LDS only in the epilogue.
__global__ __launch_bounds__(512) void deform_main(const float* __restrict__ X,
                                                   const float* __restrict__ WT,
                                                   const float* __restrict__ A,
                                                   float* __restrict__ out) {
    __shared__ float P[4 * 64 * 13];  // upper-half partials

    const int tid  = threadIdx.x;
    const int lane = tid & 63;
    const int wv   = __builtin_amdgcn_readfirstlane(tid >> 6);  // 0..7 uniform
    const int b    = wv & 3;
    const int half = wv >> 2;
    const int v0   = blockIdx.x * 64;
    const int v    = v0 + lane;
    const bool valid = (v < Vv);

    // WT column slice: per c one coalesced dword (256B-aligned run of 64)
    const float* __restrict__ Wcol = WT + (size_t)(half * 80) * VPAD + v0 + lane;
    // A: uniform base -> s_load
    const float* __restrict__ Ab = A + ((size_t)b * Cv + (size_t)half * 80) * 12;

    float acc[12];
#pragma unroll
    for (int j = 0; j < 12; ++j) acc[j] = 0.0f;

#pragma unroll 2
    for (int c4 = 0; c4 < 20; ++c4) {
#pragma unroll
        for (int j = 0; j < 4; ++j) {
            int c = c4 * 4 + j;
            float w = Wcol[(size_t)c * VPAD];             // global_load_dword
            const float* a = Ab + (size_t)c * 12;         // uniform -> s_load
#pragma unroll
            for (int k = 0; k < 12; ++k) acc[k] = fmaf(w, a[k], acc[k]);
        }
    }

    // Combine K-halves: upper waves dump partials, lower waves reduce.
    if (half) {
        float* p = &P[(b * 64 + lane) * 13];
#pragma unroll
        for (int j = 0; j < 12; ++j) p[j] = acc[j];
    }
    __syncthreads();

    if (!half && valid) {
        const float* p = &P[(b * 64 + lane) * 13];
#pragma unroll
        for (int j = 0; j < 12; ++j) acc[j] += p[j];

        const float* xp = X + ((size_t)b * Vv + v) * 3;
        float x0 = xp[0], x1 = xp[1], x2 = xp[2];
        // acc[0..8] = M row-major, acc[9..11] = T
        float o0 = acc[0]*x0 + acc[1]*x1 + acc[2]*x2 + acc[9];
        float o1 = acc[3]*x0 + acc[4]*x1 + acc[5]*x2 + acc[10];
        float o2 = acc[6]*x0 + acc[7]*x1 + acc[8]*x2 + acc[11];
        float* op = out + ((size_t)b * Vv + v) * 3;
        op[0] = o0; op[1] = o1; op[2] = o2;
    }
}

extern "C" void kernel_launch(void* const* d_in, const int* in_sizes, int n_in,
                              void* d_out, int out_size, void* d_ws, size_t ws_size,
                              hipStream_t stream) {
    const float* X   = (const float*)d_in[0];  // (B,V,3) fp32
    const float* Vn  = (const float*)d_in[1];  // (B,C,3) fp32
    const float* r6  = (const float*)d_in[2];  // (B,C,6) fp32
    const float* W   = (const float*)d_in[3];  // (V,C)   fp32
    const int*   idx = (const int*)d_in[4];    // (C,)    int32
    float* out = (float*)d_out;                // (B,V,3) fp32

    float* A  = (float*)d_ws;                           // 30720 B
    float* WT = (float*)((char*)d_ws + 32768);          // C*VPAD*4 = 32.0 MB

    precompute_A<<<(Bv * Cv + 255) / 256, 256, 0, stream>>>(X, Vn, r6, idx, A);
    transpose_W<<<TILES, 256, 0, stream>>>(W, WT);
    deform_main<<<TILES, 512, 0, stream>>>(X, WT, A, out);
}

// Round 12
// 87.992 us; speedup vs baseline: 1.2910x; 1.2910x over previous
//
#include <hip/hip_runtime.h>

#define Bv 4
#define Vv 50000
#define Cv 160
#define TILES 782      // ceil(Vv/64)
#define WSTR 168       // bf16/row in LDS: 336 B = 21*16 (b128-aligned rows)

typedef unsigned short u16;
typedef unsigned int   u32;
typedef __attribute__((ext_vector_type(8))) short bf16x8;  // 8 bf16 = 4 VGPRs
typedef __attribute__((ext_vector_type(4))) float f32x4;

__device__ __forceinline__ u16 f2bf(float f) {
    u32 u = __float_as_uint(f);
    return (u16)((u + 0x7FFFu + ((u >> 16) & 1u)) >> 16);  // RNE
}

// Kernel 1: rotation-6d -> per-(b,c) affine [R | T], written as bf16 AT
// table laid out [n][c] with n = b*12 + j (j: 0..8 = R row-major, 9..11 = T
// = center + Vn - R*center). So out[b,v,:] = M.x_v + T with
// [M|T](v,b) = sum_c W[v,c] * AT[b*12+j][c]  — a 50000x48x160 GEMM.
__global__ void precompute_AT(const float* __restrict__ X,
                              const float* __restrict__ Vn,
                              const float* __restrict__ r6,
                              const int* __restrict__ idx,
                              u16* __restrict__ AT) {
    int i = blockIdx.x * blockDim.x + threadIdx.x;
    if (i >= Bv * Cv) return;
    int b = i / Cv, c = i % Cv;

    const float* d6 = r6 + (size_t)(b * Cv + c) * 6;
    float a1x = d6[0], a1y = d6[1], a1z = d6[2];
    float a2x = d6[3], a2y = d6[4], a2z = d6[5];

    float n1 = fmaxf(sqrtf(a1x*a1x + a1y*a1y + a1z*a1z), 1e-8f);
    float b1x = a1x / n1, b1y = a1y / n1, b1z = a1z / n1;

    float d = b1x*a2x + b1y*a2y + b1z*a2z;
    float px = a2x - d*b1x, py = a2y - d*b1y, pz = a2z - d*b1z;
    float n2 = fmaxf(sqrtf(px*px + py*py + pz*pz), 1e-8f);
    float b2x = px / n2, b2y = py / n2, b2z = pz / n2;

    float b3x = b1y*b2z - b1z*b2y;
    float b3y = b1z*b2x - b1x*b2z;
    float b3z = b1x*b2y - b1y*b2x;

    int iv = idx[c];
    const float* xc = X + ((size_t)b * Vv + iv) * 3;
    float cx = xc[0], cy = xc[1], cz = xc[2];
    const float* vn = Vn + (size_t)(b * Cv + c) * 3;
    float vx = vn[0], vy = vn[1], vz = vn[2];

    float vals[12];
    vals[0] = b1x; vals[1]  = b1y; vals[2]  = b1z;
    vals[3] = b2x; vals[4]  = b2y; vals[5]  = b2z;
    vals[6] = b3x; vals[7]  = b3y; vals[8]  = b3z;
    vals[9]  = cx + vx - (b1x*cx + b1y*cy + b1z*cz);
    vals[10] = cy + vy - (b2x*cx + b2y*cy + b2z*cz);
    vals[11] = cz + vz - (b3x*cx + b3y*cy + b3z*cz);

#pragma unroll
    for (int j = 0; j < 12; ++j)
        AT[(size_t)(b * 12 + j) * Cv + c] = f2bf(vals[j]);
}

// Kernel 2: MFMA GEMM, one 64-vertex tile per block (256 thr = 4 waves,
// wave = 16-row M-tile). P(64x48) = Wtile(64x160,bf16) x Atab(160x48,bf16)
// via 15 mfma_f32_16x16x32_bf16 per wave; fp32 epilogue out = M.x + T.
// This replaces ~1M scalar FMA + ~1M operand loads (the operand-delivery
// bottleneck of R4-R11: s_load latency / 64-line gathers / LDS broadcast
// issue) with 47k MFMAs whose operands come from the matrix file.
__global__ __launch_bounds__(256) void deform_mfma(const float* __restrict__ X,
                                                   const float* __restrict__ W,
                                                   const u16* __restrict__ ATg,
                                                   float* __restrict__ out) {
    __shared__ char smem[64 * WSTR * 2];   // 21504 B; reused as P (64*49*4 B)
    u16*   Wl = (u16*)smem;
    float* P  = (float*)smem;

    const int tid = threadIdx.x;
    const int v0  = blockIdx.x * 64;

    // Stage W tile fp32 -> bf16 LDS, coalesced float4 reads along rows.
    for (int i = tid; i < 64 * 40; i += 256) {
        int r = i / 40, c4 = i % 40;
        int row = v0 + r;
        if (row >= Vv) row = Vv - 1;          // tail tile: dup rows, epilogue guards
        float4 q = ((const float4*)(W + (size_t)row * Cv))[c4];
        ushort4 h;
        h.x = f2bf(q.x); h.y = f2bf(q.y); h.z = f2bf(q.z); h.w = f2bf(q.w);
        *(ushort4*)&Wl[r * WSTR + c4 * 4] = h;  // 8B ds_write
    }
    __syncthreads();

    const int lane = tid & 63;
    const int wv   = tid >> 6;     // M-tile 0..3 (rows 16wv..16wv+15)
    const int m    = lane & 15;
    const int quad = lane >> 4;

    // A-frags: A[m][k=quad*8+j], 16B-aligned ds_read_b128 (WSTR*2=336=21*16).
    bf16x8 afr[5];
#pragma unroll
    for (int kt = 0; kt < 5; ++kt)
        afr[kt] = *(const bf16x8*)&Wl[(wv * 16 + m) * WSTR + kt * 32 + quad * 8];

    // B-frags: B[k=quad*8+j][n=m] from AT[n][c] global (15 KB, L1/L2-warm).
    bf16x8 bfr[3][5];
#pragma unroll
    for (int nt = 0; nt < 3; ++nt)
#pragma unroll
        for (int kt = 0; kt < 5; ++kt)
            bfr[nt][kt] = *(const bf16x8*)&ATg[(size_t)(nt * 16 + m) * Cv + kt * 32 + quad * 8];

    f32x4 acc[3] = {{0,0,0,0},{0,0,0,0},{0,0,0,0}};
#pragma unroll
    for (int kt = 0; kt < 5; ++kt)
#pragma unroll
        for (int nt = 0; nt < 3; ++nt)
            acc[nt] = __builtin_amdgcn_mfma_f32_16x16x32_bf16(afr[kt], bfr[nt][kt], acc[nt], 0, 0, 0);

    __syncthreads();   // all frag reads of Wl done; safe to overwrite as P

    // C/D layout: col = lane&15, row = quad*4 + reg. P[v_local][n], stride 49.
#pragma unroll
    for (int nt = 0; nt < 3; ++nt)
#pragma unroll
        for (int r = 0; r < 4; ++r)
            P[(wv * 16 + quad * 4 + r) * 49 + nt * 16 + m] = acc[nt][r];
    __syncthreads();

    // Epilogue: thread -> (b = tid>>6, v_local = tid&63), fp32 M.x + T.
    const int b  = tid >> 6;
    const int vl = tid & 63;
    const int v  = v0 + vl;
    if (v < Vv) {
        const float* p = &P[vl * 49 + b * 12];
        const float* xp = X + ((size_t)b * Vv + v) * 3;
        float x0 = xp[0], x1 = xp[1], x2 = xp[2];
        float* op = out + ((size_t)b * Vv + v) * 3;
        op[0] = p[0]*x0 + p[1]*x1 + p[2]*x2 + p[9];
        op[1] = p[3]*x0 + p[4]*x1 + p[5]*x2 + p[10];
        op[2] = p[6]*x0 + p[7]*x1 + p[8]*x2 + p[11];
    }
}

extern "C" void kernel_launch(void* const* d_in, const int* in_sizes, int n_in,
                              void* d_out, int out_size, void* d_ws, size_t ws_size,
                              hipStream_t stream) {
    const float* X   = (const float*)d_in[0];  // (B,V,3) fp32
    const float* Vn  = (const float*)d_in[1];  // (B,C,3) fp32
    const float* r6  = (const float*)d_in[2];  // (B,C,6) fp32
    const float* W   = (const float*)d_in[3];  // (V,C)   fp32
    const int*   idx = (const int*)d_in[4];    // (C,)    int32
    float* out = (float*)d_out;                // (B,V,3) fp32

    u16* AT = (u16*)d_ws;                      // 48*160*2 = 15360 B

    precompute_AT<<<(Bv * Cv + 255) / 256, 256, 0, stream>>>(X, Vn, r6, idx, AT);
    deform_mfma<<<TILES, 256, 0, stream>>>(X, W, AT, out);
}